// Round 1
// 3764.827 us; speedup vs baseline: 1.1534x; 1.1534x over previous
//
#include <hip/hip_runtime.h>
#include <hip/hip_bf16.h>
#include <cstdint>
#include <cstddef>

#define BB 64
#define TT 512
#define DD 256
#define HH 512
#define G4 2048   // 4*H

typedef __bf16 bf16x8 __attribute__((ext_vector_type(8)));
typedef __bf16 bf16x4 __attribute__((ext_vector_type(4)));
typedef float  f32x4  __attribute__((ext_vector_type(4)));
typedef unsigned long long ull_t;

__device__ __forceinline__ float sigf(float x) {
  return 1.0f / (1.0f + __expf(-x));
}

// Agent-coherent (cross-XCD) accesses for the h ping-pong buffer. RELAXED+AGENT
// emits per-access coherence bits (write-through / L2-bypass) WITHOUT the
// whole-L2 buffer_inv / buffer_wbl2 that ACQUIRE/RELEASE fences emit.
__device__ __forceinline__ ull_t coh_load_u64(const __bf16* p) {
  return __hip_atomic_load(reinterpret_cast<const ull_t*>(p),
                           __ATOMIC_RELAXED, __HIP_MEMORY_SCOPE_AGENT);
}
__device__ __forceinline__ void coh_store_bf16(__bf16* p, float v) {
  union { __bf16 b; unsigned short u; } cv;
  cv.b = (__bf16)v;
  __hip_atomic_store(reinterpret_cast<unsigned short*>(p), cv.u,
                     __ATOMIC_RELAXED, __HIP_MEMORY_SCOPE_AGENT);
}

// Convert x fp32 [B][T][D] -> bf16 (same layout) in ws.
__global__ void cvt_x_kernel(const float* __restrict__ x, __bf16* __restrict__ xb) {
  int i = (blockIdx.x * 256 + threadIdx.x) * 4;
  float4 v = *(const float4*)(x + i);
  bf16x4 o;
  o[0] = (__bf16)v.x; o[1] = (__bf16)v.y; o[2] = (__bf16)v.z; o[3] = (__bf16)v.w;
  *(bf16x4*)(xb + i) = o;
}

// Persistent bidirectional LSTM.
// Grid: 64 blocks x 256 threads. dir = blockIdx>>5 (0 fwd, 1 bwd), s = blockIdx&31
// owns hidden units [16s, 16s+16). Wave (tid>>6) = M-tile (16 batch rows).
// Sync per step: producers store h via write-through agent-coherent stores,
// __syncthreads() drains vmcnt (stores globally visible), tid0 does a RELAXED
// agent fetch_add; consumers spin on a RELAXED agent load (no cache maintenance)
// and gather h via agent-coherent u64 loads from the coherence point.
__launch_bounds__(256, 1)
__global__ void lstm_kernel(const __bf16* __restrict__ xb,
                            const float* __restrict__ Wf, const float* __restrict__ Uf,
                            const float* __restrict__ bf_,
                            const float* __restrict__ Wb, const float* __restrict__ Ub,
                            const float* __restrict__ bb_,
                            __bf16* __restrict__ hbuf,          // [2 dir][2 phase][64][512]
                            unsigned int* __restrict__ counters, // [2] (64-int stride)
                            float* __restrict__ out,            // d_out
                            __bf16* __restrict__ hsb) {         // [T][B][H] bwd halves
  const int bx  = blockIdx.x;
  const int dir = bx >> 5;
  const int s   = bx & 31;
  const float* Wd = dir ? Wb : Wf;
  const float* Ud = dir ? Ub : Uf;
  const float* bd = dir ? bb_ : bf_;
  unsigned int* cnt = counters + dir * 64;
  __bf16* hb = hbuf + (size_t)dir * 2 * BB * HH;

  const int tid  = threadIdx.x;
  const int mt   = tid >> 6;      // wave id = M-tile
  const int lane = tid & 63;
  const int j    = lane & 15;     // A row offset / B col / D col
  const int q    = lane >> 4;     // quad
  const int colg = s * 16 + j;    // hidden unit index this lane owns

  // ---- gather weight B-fragments (one-time) ----
  bf16x8 wfrag[4][24];
#pragma unroll
  for (int g = 0; g < 4; ++g) {
    const int col = g * HH + colg;
#pragma unroll
    for (int kt = 0; kt < 24; ++kt) {
      bf16x8 v;
#pragma unroll
      for (int e = 0; e < 8; ++e) {
        const int k = kt * 32 + q * 8 + e;
        const float w = (k < DD) ? Wd[(size_t)k * G4 + col]
                                 : Ud[(size_t)(k - DD) * G4 + col];
        v[e] = (__bf16)w;
      }
      wfrag[g][kt] = v;
    }
  }
  float bg[4];
#pragma unroll
  for (int g = 0; g < 4; ++g) bg[g] = bd[g * HH + colg];

  float cst[4] = {0.f, 0.f, 0.f, 0.f};   // cell state, rows mt*16+q*4+r
  const size_t outTail = (size_t)BB * TT * HH;

  for (int tau = 0; tau < TT; ++tau) {
    const int t = dir ? (TT - 1 - tau) : tau;

    // h-row base for this step (address VALU done before the spin)
    const __bf16* hrow = hb + (size_t)(tau & 1) * (BB * HH) + (size_t)(mt * 16 + j) * HH + q * 8;

    // x-part (independent of h): issue before the spin
    const __bf16* xrow = xb + ((size_t)(mt * 16 + j) * TT + t) * DD + q * 8;
    f32x4 acc[4];
#pragma unroll
    for (int g = 0; g < 4; ++g) acc[g] = (f32x4){bg[g], bg[g], bg[g], bg[g]};
#pragma unroll
    for (int kt = 0; kt < 8; ++kt) {
      bf16x8 a = *(const bf16x8*)(xrow + kt * 32);
#pragma unroll
      for (int g = 0; g < 4; ++g)
        acc[g] = __builtin_amdgcn_mfma_f32_16x16x32_bf16(a, wfrag[g][kt], acc[g], 0, 0, 0);
    }

    // wait until all blocks of this direction published h_tau.
    // All lanes poll the same address (one coalesced request per wave);
    // RELAXED => no buffer_inv per iteration.
    if (tau) {
      const unsigned int target = 32u * (unsigned int)tau;
      while (__hip_atomic_load(cnt, __ATOMIC_RELAXED, __HIP_MEMORY_SCOPE_AGENT) < target) {
        __builtin_amdgcn_s_sleep(1);
      }
      __atomic_signal_fence(__ATOMIC_ACQUIRE);   // compiler: no hoisting of h loads
      __builtin_amdgcn_sched_barrier(0);
    }

    // h-part: agent-coherent gather, software-pipelined in batches of 4 K-tiles
    {
      ull_t pre[8];
      ull_t nxt[8];
#pragma unroll
      for (int i = 0; i < 4; ++i) {
        pre[2*i]   = coh_load_u64(hrow + i * 32);
        pre[2*i+1] = coh_load_u64(hrow + i * 32 + 4);
      }
#pragma unroll
      for (int kb = 0; kb < 4; ++kb) {
        if (kb < 3) {
#pragma unroll
          for (int i = 0; i < 4; ++i) {
            nxt[2*i]   = coh_load_u64(hrow + ((kb + 1) * 4 + i) * 32);
            nxt[2*i+1] = coh_load_u64(hrow + ((kb + 1) * 4 + i) * 32 + 4);
          }
        }
#pragma unroll
        for (int i = 0; i < 4; ++i) {
          union { ull_t q[2]; bf16x8 v; } uu;
          uu.q[0] = pre[2*i]; uu.q[1] = pre[2*i+1];
          const int kt = kb * 4 + i;
#pragma unroll
          for (int g = 0; g < 4; ++g)
            acc[g] = __builtin_amdgcn_mfma_f32_16x16x32_bf16(uu.v, wfrag[g][8 + kt], acc[g], 0, 0, 0);
        }
        if (kb < 3) {
#pragma unroll
          for (int i = 0; i < 8; ++i) pre[i] = nxt[i];
        }
      }
    }

    // gates + state update + stores (all-sigmoid variant per reference)
    __bf16* hnext = hb + (size_t)((tau + 1) & 1) * (BB * HH);
#pragma unroll
    for (int r = 0; r < 4; ++r) {
      const float zi = acc[0][r], zf = acc[1][r], zg = acc[2][r], zo = acc[3][r];
      const float gi = sigf(zi), gf = sigf(zf), gg = sigf(zg), go = sigf(zo);
      const float cn = gf * cst[r] + gi * gg;
      cst[r] = cn;
      const float hn = go * sigf(cn);
      const int orow = mt * 16 + q * 4 + r;     // batch row
      coh_store_bf16(&hnext[(size_t)orow * HH + colg], hn);   // write-through, coherent
      if (dir == 0) {
        out[(size_t)orow * (TT * HH) + (size_t)t * HH + colg] = 0.5f * hn;
      } else {
        hsb[(size_t)t * (BB * HH) + (size_t)orow * HH + colg] = (__bf16)hn;
      }
      if (tau == TT - 1) {
        float* base = out + outTail + (size_t)dir * (2 * BB * HH);
        base[(size_t)orow * HH + colg] = hn;                 // hF / hB
        base[(size_t)BB * HH + (size_t)orow * HH + colg] = cn; // cF / cB
      }
    }

    // __syncthreads drains vmcnt(0) per wave => all write-through h stores of
    // this block are globally visible before tid0's relaxed increment.
    __atomic_signal_fence(__ATOMIC_RELEASE);
    __syncthreads();
    if (tid == 0)
      __hip_atomic_fetch_add(cnt, 1u, __ATOMIC_RELAXED, __HIP_MEMORY_SCOPE_AGENT);
  }
}

// out[b,t,c] += 0.5 * hsb[t,b,c]
__global__ void combine_kernel(float* __restrict__ out, const __bf16* __restrict__ hsb) {
  const size_t i = ((size_t)blockIdx.x * 256 + threadIdx.x) * 4;
  const size_t b = i >> 18;
  const size_t t = (i >> 9) & 511;
  const size_t c = i & 511;
  bf16x4 hv = *(const bf16x4*)(hsb + t * (BB * HH) + b * HH + c);
  float4 v = *(float4*)(out + i);
  v.x += 0.5f * (float)hv[0];
  v.y += 0.5f * (float)hv[1];
  v.z += 0.5f * (float)hv[2];
  v.w += 0.5f * (float)hv[3];
  *(float4*)(out + i) = v;
}

extern "C" void kernel_launch(void* const* d_in, const int* in_sizes, int n_in,
                              void* d_out, int out_size, void* d_ws, size_t ws_size,
                              hipStream_t stream) {
  (void)in_sizes; (void)n_in; (void)out_size; (void)ws_size;
  const float* x   = (const float*)d_in[0];
  // d_in[1] = 'hidden' is unused by the reference (h0 = c0 = 0)
  const float* Wf  = (const float*)d_in[2];
  const float* Uf  = (const float*)d_in[3];
  const float* bf_ = (const float*)d_in[4];
  const float* Wb  = (const float*)d_in[5];
  const float* Ub  = (const float*)d_in[6];
  const float* bb_ = (const float*)d_in[7];
  float* out = (float*)d_out;
  char* ws = (char*)d_ws;

  // ws layout:
  //   [0, 256)        : counters (2 used, 256B apart)
  //   [1024, 263168)  : hbuf  2 dir x 2 phase x 64 x 512 bf16
  //   [512K, 16.5M)   : x bf16 [B][T][D]
  //   [16.5M, 48.5M)  : hsb bf16 [T][B][H]
  unsigned int* counters = (unsigned int*)ws;
  __bf16* hbuf = (__bf16*)(ws + 1024);
  __bf16* xb   = (__bf16*)(ws + (1 << 19));
  __bf16* hsb  = (__bf16*)(ws + (1 << 19) + (size_t)BB * TT * DD * 2);

  hipMemsetAsync(ws, 0, 1 << 19, stream);  // zero counters + h ping-pong (h0 = 0)
  cvt_x_kernel<<<dim3((BB * TT * DD) / 1024), dim3(256), 0, stream>>>(x, xb);
  lstm_kernel<<<dim3(64), dim3(256), 0, stream>>>(xb, Wf, Uf, bf_, Wb, Ub, bb_,
                                                  hbuf, counters, out, hsb);
  combine_kernel<<<dim3((BB * TT * HH) / 1024), dim3(256), 0, stream>>>(out, hsb);
}

// Round 2
// 3757.965 us; speedup vs baseline: 1.1555x; 1.0018x over previous
//
#include <hip/hip_runtime.h>
#include <hip/hip_bf16.h>
#include <cstdint>
#include <cstddef>

#define BB 64
#define TT 512
#define DD 256
#define HH 512
#define G4 2048   // 4*H

typedef __bf16 bf16x8 __attribute__((ext_vector_type(8)));
typedef __bf16 bf16x4 __attribute__((ext_vector_type(4)));
typedef float  f32x4  __attribute__((ext_vector_type(4)));
typedef unsigned long long ull_t;

// bits[15:14] of every bf16 h element are the step tag:
//   00 = never occurs in fresh data (valid h in (0,1) has bits 00, but producers OR a tag in)
//   01 / 10 = alternating step tags (1 + ((step>>1)&1))
//   11 = init sentinel (memset 0xFF)
#define TAGM 0xC000C000C000C000ULL

__device__ __forceinline__ float sigf(float x) {
  return 1.0f / (1.0f + __expf(-x));
}

// Agent-coherent (cross-XCD) accesses for the h ping-pong buffer. RELAXED+AGENT
// emits per-access coherence bits (bypass non-coherent caches, hit the MALL)
// without any whole-cache maintenance ops.
__device__ __forceinline__ ull_t coh_load_u64(const __bf16* p) {
  return __hip_atomic_load(reinterpret_cast<const ull_t*>(p),
                           __ATOMIC_RELAXED, __HIP_MEMORY_SCOPE_AGENT);
}
__device__ __forceinline__ void coh_store_u16(__bf16* p, unsigned short v) {
  __hip_atomic_store(reinterpret_cast<unsigned short*>(p), v,
                     __ATOMIC_RELAXED, __HIP_MEMORY_SCOPE_AGENT);
}

// Convert x fp32 [B][T][D] -> bf16 (same layout) in ws.
__global__ void cvt_x_kernel(const float* __restrict__ x, __bf16* __restrict__ xb) {
  int i = (blockIdx.x * 256 + threadIdx.x) * 4;
  float4 v = *(const float4*)(x + i);
  bf16x4 o;
  o[0] = (__bf16)v.x; o[1] = (__bf16)v.y; o[2] = (__bf16)v.z; o[3] = (__bf16)v.w;
  *(bf16x4*)(xb + i) = o;
}

// Persistent bidirectional LSTM, tag-in-data synchronization (no barriers, no
// counters, no fences). Grid: 64 blocks x 256 threads. dir = blockIdx>>5,
// s = blockIdx&31 owns hidden units [16s,16s+16). Wave (tid>>6) = M-tile of 16
// batch rows; the 4 waves of a block are fully independent.
// Per step: acc = bias; 8 x-kt MFMAs; then per 4-kt batch poll the h fragment
// u64s until all 16b elements carry this step's tag, strip tags, 16 h-kt MFMAs;
// gates; publish h_{tau+1} as tagged write-through bf16 stores (tag and datum in
// the same 2B store => sync needs no ordering at all).
__launch_bounds__(256, 1)
__global__ void lstm_kernel(const __bf16* __restrict__ xb,
                            const float* __restrict__ Wf, const float* __restrict__ Uf,
                            const float* __restrict__ bf_,
                            const float* __restrict__ Wb, const float* __restrict__ Ub,
                            const float* __restrict__ bb_,
                            __bf16* __restrict__ hbuf,          // [2 dir][2 phase][64][512]
                            float* __restrict__ out,            // d_out
                            __bf16* __restrict__ hsb) {         // [T][B][H] bwd halves
  const int bx  = blockIdx.x;
  const int dir = bx >> 5;
  const int s   = bx & 31;
  const float* Wd = dir ? Wb : Wf;
  const float* Ud = dir ? Ub : Uf;
  const float* bd = dir ? bb_ : bf_;
  __bf16* hb = hbuf + (size_t)dir * 2 * BB * HH;

  const int tid  = threadIdx.x;
  const int mt   = tid >> 6;      // wave id = M-tile
  const int lane = tid & 63;
  const int j    = lane & 15;     // A row offset / B col / D col
  const int q    = lane >> 4;     // quad
  const int colg = s * 16 + j;    // hidden unit index this lane owns

  // ---- gather weight B-fragments (one-time) ----
  bf16x8 wfrag[4][24];
#pragma unroll
  for (int g = 0; g < 4; ++g) {
    const int col = g * HH + colg;
#pragma unroll
    for (int kt = 0; kt < 24; ++kt) {
      bf16x8 v;
#pragma unroll
      for (int e = 0; e < 8; ++e) {
        const int k = kt * 32 + q * 8 + e;
        const float w = (k < DD) ? Wd[(size_t)k * G4 + col]
                                 : Ud[(size_t)(k - DD) * G4 + col];
        v[e] = (__bf16)w;
      }
      wfrag[g][kt] = v;
    }
  }
  float bg[4];
#pragma unroll
  for (int g = 0; g < 4; ++g) bg[g] = bd[g * HH + colg];

  float cst[4] = {0.f, 0.f, 0.f, 0.f};   // cell state, rows mt*16+q*4+r
  const size_t outTail = (size_t)BB * TT * HH;

  for (int tau = 0; tau < TT; ++tau) {
    const int t = dir ? (TT - 1 - tau) : tau;

    // x-part (independent of h)
    const __bf16* xrow = xb + ((size_t)(mt * 16 + j) * TT + t) * DD + q * 8;
    f32x4 acc[4];
#pragma unroll
    for (int g = 0; g < 4; ++g) acc[g] = (f32x4){bg[g], bg[g], bg[g], bg[g]};
#pragma unroll
    for (int kt = 0; kt < 8; ++kt) {
      bf16x8 a = *(const bf16x8*)(xrow + kt * 32);
#pragma unroll
      for (int g = 0; g < 4; ++g)
        acc[g] = __builtin_amdgcn_mfma_f32_16x16x32_bf16(a, wfrag[g][kt], acc[g], 0, 0, 0);
    }

    // h-part: poll-the-data (tag bits carry the sync), then MFMA.
    if (tau) {
      const __bf16* hrow = hb + (size_t)(tau & 1) * (BB * HH)
                              + (size_t)(mt * 16 + j) * HH + q * 8;
      const ull_t epat = (ull_t)(1u + ((unsigned)(tau >> 1) & 1u)) * 0x4000400040004000ULL;
#pragma unroll
      for (int kb = 0; kb < 4; ++kb) {
        ull_t d[8];
        int ok;
        do {
#pragma unroll
          for (int i = 0; i < 4; ++i) {
            d[2*i]   = coh_load_u64(hrow + (kb * 4 + i) * 32);
            d[2*i+1] = coh_load_u64(hrow + (kb * 4 + i) * 32 + 4);
          }
          ok = 1;
#pragma unroll
          for (int i = 0; i < 8; ++i) ok &= ((d[i] & TAGM) == epat);
        } while (!__all(ok));
#pragma unroll
        for (int i = 0; i < 4; ++i) {
          union { ull_t u[2]; bf16x8 v; } uu;
          uu.u[0] = d[2*i]   & ~TAGM;
          uu.u[1] = d[2*i+1] & ~TAGM;
          const int kt = kb * 4 + i;
#pragma unroll
          for (int g = 0; g < 4; ++g)
            acc[g] = __builtin_amdgcn_mfma_f32_16x16x32_bf16(uu.v, wfrag[g][8 + kt], acc[g], 0, 0, 0);
        }
      }
    }

    // gates + state update + publish tagged h (all-sigmoid variant per reference)
    const unsigned short ptag =
        (unsigned short)((1u + ((unsigned)((tau + 1) >> 1) & 1u)) << 14);
    __bf16* hnext = hb + (size_t)((tau + 1) & 1) * (BB * HH);
#pragma unroll
    for (int r = 0; r < 4; ++r) {
      const float zi = acc[0][r], zf = acc[1][r], zg = acc[2][r], zo = acc[3][r];
      const float gi = sigf(zi), gf = sigf(zf), gg = sigf(zg), go = sigf(zo);
      const float cn = gf * cst[r] + gi * gg;
      cst[r] = cn;
      const float hn = go * sigf(cn);
      const int orow = mt * 16 + q * 4 + r;     // batch row
      union { __bf16 b; unsigned short u; } cv;
      cv.b = (__bf16)hn;                         // hn in (0,1) => bits[15:14] == 00
      coh_store_u16(&hnext[(size_t)orow * HH + colg],
                    (unsigned short)(cv.u | ptag));
      if (dir == 0) {
        out[(size_t)orow * (TT * HH) + (size_t)t * HH + colg] = 0.5f * hn;
      } else {
        hsb[(size_t)t * (BB * HH) + (size_t)orow * HH + colg] = (__bf16)hn;
      }
      if (tau == TT - 1) {
        float* base = out + outTail + (size_t)dir * (2 * BB * HH);
        base[(size_t)orow * HH + colg] = hn;                 // hF / hB
        base[(size_t)BB * HH + (size_t)orow * HH + colg] = cn; // cF / cB
      }
    }
  }
}

// out[b,t,c] += 0.5 * hsb[t,b,c]
__global__ void combine_kernel(float* __restrict__ out, const __bf16* __restrict__ hsb) {
  const size_t i = ((size_t)blockIdx.x * 256 + threadIdx.x) * 4;
  const size_t b = i >> 18;
  const size_t t = (i >> 9) & 511;
  const size_t c = i & 511;
  bf16x4 hv = *(const bf16x4*)(hsb + t * (BB * HH) + b * HH + c);
  float4 v = *(float4*)(out + i);
  v.x += 0.5f * (float)hv[0];
  v.y += 0.5f * (float)hv[1];
  v.z += 0.5f * (float)hv[2];
  v.w += 0.5f * (float)hv[3];
  *(float4*)(out + i) = v;
}

extern "C" void kernel_launch(void* const* d_in, const int* in_sizes, int n_in,
                              void* d_out, int out_size, void* d_ws, size_t ws_size,
                              hipStream_t stream) {
  (void)in_sizes; (void)n_in; (void)out_size; (void)ws_size;
  const float* x   = (const float*)d_in[0];
  // d_in[1] = 'hidden' is unused by the reference (h0 = c0 = 0)
  const float* Wf  = (const float*)d_in[2];
  const float* Uf  = (const float*)d_in[3];
  const float* bf_ = (const float*)d_in[4];
  const float* Wb  = (const float*)d_in[5];
  const float* Ub  = (const float*)d_in[6];
  const float* bb_ = (const float*)d_in[7];
  float* out = (float*)d_out;
  char* ws = (char*)d_ws;

  // ws layout:
  //   [1024, 263168)  : hbuf  2 dir x 2 phase x 64 x 512 bf16 (0xFF = init sentinel)
  //   [512K, 16.5M)   : x bf16 [B][T][D]
  //   [16.5M, 48.5M)  : hsb bf16 [T][B][H]
  __bf16* hbuf = (__bf16*)(ws + 1024);
  __bf16* xb   = (__bf16*)(ws + (1 << 19));
  __bf16* hsb  = (__bf16*)(ws + (1 << 19) + (size_t)BB * TT * DD * 2);

  hipMemsetAsync(ws, 0xFF, 1 << 19, stream);  // tag 11 = "never written" sentinel
  cvt_x_kernel<<<dim3((BB * TT * DD) / 1024), dim3(256), 0, stream>>>(x, xb);
  lstm_kernel<<<dim3(64), dim3(256), 0, stream>>>(xb, Wf, Uf, bf_, Wb, Ub, bb_,
                                                  hbuf, out, hsb);
  combine_kernel<<<dim3((BB * TT * HH) / 1024), dim3(256), 0, stream>>>(out, hsb);
}